// Round 2
// baseline (2199.808 us; speedup 1.0000x reference)
//
#include <hip/hip_runtime.h>
#include <cstddef>

// NLM: h=7/255, template 7x7 (TH=3), search 21x21 (SH=10), reflect padding.
// Tile 32x32/block, 256 threads, software-pipelined disjoint wave roles,
// double-buffered vsh, ONE barrier per offset.
// R5: packed-fp32 Bv + exp2 prescale.
//   FAST blocks (interior in x AND y, 900/1024): Bv = 57 lanes (wave 0 only),
//     each owning a COLUMN PAIR as float2 -> v_pk_*_f32 arithmetic,
//     ds_read_b64/ds_write_b64. One Bv wave instead of two.
//   EDGE blocks: proven scalar Bv (17 per-row reflected addresses, 114 lanes).
//   xs is pre-scaled by LAM = sqrt(-K) so the horizontal 7-sum is already
//     -K*s and w = exp2(-h) uses the free source-negate modifier (kills the
//     8 h*K muls per C-lane-iter). Epilogue divides by LAM once.
// R2 lesson kept: no unrolling of the offset loop.

typedef float v2f __attribute__((ext_vector_type(2)));

constexpr int TS    = 32;
constexpr int XSTR  = 62;            // EVEN -> float2 (b64) col-pair packing
constexpr int XROWS = 59;            // image rows gy0-13 .. gy0+45
constexpr int XSZ   = XROWS * XSTR;  // 3658
constexpr int VSTR  = 42;            // even (float2-aligned), banks shift 10/row
constexpr int VROWS = 33;            // 32 + 1 junk row (group-2 uniform writes)
constexpr int VS_SZ = VROWS * VSTR;  // 1386 per buffer

__device__ __forceinline__ int refl(int i, int n) {
    i = (i < 0) ? -i : i;
    return (i >= n) ? (2 * n - 2 - i) : i;
}

template<bool FAST>
__device__ __forceinline__ void nlm_body(const float* __restrict__ img,
                                         float* __restrict__ out,
                                         int H, int W, int gx0, int gy0,
                                         float* xs, float* vsh, int tid)
{
    const float NK  = (65025.0f / 2401.0f) * 1.4426950408889634f;  // -K > 0
    const float LAM = sqrtf(NK);

    // ---- load xs (clip to [0,1], reflect indexing, pre-scale by LAM) ----
    for (int e = tid; e < XSZ; e += 256) {
        int i = e / XSTR, j = e - i * XSTR;
        int jj = (j > 57) ? 57 : j;  // cols 58..61: stride pad (never read)
        int gy = refl(gy0 - 13 + i, H);
        int gx = refl(gx0 - 13 + jj, W);
        float v = img[(size_t)gy * W + gx];
        xs[e] = fminf(fmaxf(v, 0.0f), 1.0f) * LAM;
    }
    __syncthreads();

    // ---- Bv setup ----
    const bool bv = FAST ? (tid < 57) : (tid < 114);
    v2f   uP[17]; int aB = 0;        // FAST state (col-pair packed)
    float uS[17]; int aS[17];        // EDGE state (scalar, reflected rows)
    int   wb = 0;
    if constexpr (FAST) {
        int t  = bv ? tid : 0;
        int g  = t / 19;             // 0..2 row group
        int pp = t - g * 19;         // 0..18 column pair
        int r  = g * 11;             // first output row of this group
        int cc = 2 * pp;             // interior: mxm10 == cc, cols linear
        aB = r * XSTR + cc;
        wb = r * VSTR + cc;
#pragma unroll
        for (int i = 0; i < 17; ++i)
            uP[i] = *reinterpret_cast<const v2f*>(&xs[(r + i + 10) * XSTR + cc + 10]);
    } else {
        int t  = bv ? tid : 0;
        int g  = t / 38;
        int cc = t - g * 38;
        int r  = g * 11;
        int mxm10 = refl(gx0 + cc - 3, W) - gx0 + 3;
#pragma unroll
        for (int i = 0; i < 17; ++i) {
            int my = refl(gy0 + r + i - 3, H) - gy0 + 13;
            uS[i] = xs[my * XSTR + mxm10 + 10];
            aS[i] = (my - 10) * XSTR + mxm10;
        }
        wb = r * VSTR + cc;
    }

    // ---- C setup ----
    const bool cact = (tid >= 128);
    const int ct = cact ? (tid - 128) : 0;
    const int py = ct >> 2;
    const int c8 = (ct & 3) * 8;
    const int vb = py * VSTR + c8;              // float2-aligned (even)
    int svC = (py + 3) * XSTR + (c8 + 3);       // row base, advances per oy

    int oxB = 0;                                 // uniform ox state machines
    int oxC = 0;

    float p[7];
    float ws[8], ac[8];
#pragma unroll
    for (int k = 0; k < 8; ++k) { ws[k] = 0.f; ac[k] = 0.f; }

    auto bv_step = [&](int buf) {
        if (bv) {
            float* vo = vsh + buf * VS_SZ + wb;
            if constexpr (FAST) {
                v2f q[17];
#pragma unroll
                for (int i = 0; i < 7; ++i) {
                    v2f sh = *reinterpret_cast<const v2f*>(&xs[aB + i * XSTR]);
                    v2f d = uP[i] - sh;
                    q[i] = d * d;
                }
                v2f s = ((q[0] + q[1]) + (q[2] + q[3])) + ((q[4] + q[5]) + q[6]);
                *reinterpret_cast<v2f*>(vo) = s;
#pragma unroll
                for (int k = 1; k < 11; ++k) {
                    v2f sh = *reinterpret_cast<const v2f*>(&xs[aB + (k + 6) * XSTR]);
                    v2f d = uP[k + 6] - sh;
                    q[k + 6] = d * d;
                    s += q[k + 6] - q[k - 1];
                    *reinterpret_cast<v2f*>(&vo[k * VSTR]) = s;
                }
                aB += (oxB == 20) ? (XSTR - 20) : 1;
            } else {
                float q[17];
#pragma unroll
                for (int i = 0; i < 7; ++i) {
                    float d = uS[i] - xs[aS[i]];
                    q[i] = d * d;
                }
                float s = ((q[0] + q[1]) + (q[2] + q[3])) + ((q[4] + q[5]) + q[6]);
                vo[0] = s;
#pragma unroll
                for (int k = 1; k < 11; ++k) {
                    float d = uS[k + 6] - xs[aS[k + 6]];
                    q[k + 6] = d * d;
                    s += q[k + 6] - q[k - 1];
                    vo[k * VSTR] = s;
                }
                int step = (oxB == 20) ? (XSTR - 20) : 1;
#pragma unroll
                for (int i = 0; i < 17; ++i) aS[i] += step;
            }
        }
        oxB = (oxB == 20) ? 0 : (oxB + 1);
    };

    auto c_step = [&](int buf) {
        if (cact) {
            if (oxC == 0) {
#pragma unroll
                for (int k = 0; k < 7; ++k) p[k] = xs[svC + k];
            }
            const v2f* vp = reinterpret_cast<const v2f*>(vsh + buf * VS_SZ + vb);
            v2f tA = vp[0], tB = vp[1], tC = vp[2], tD = vp[3];
            v2f tE = vp[4], tF = vp[5], tG = vp[6];
            float p7 = xs[svC + 7 + oxC];
            float h0 = ((tA.x + tA.y) + (tB.x + tB.y)) + ((tC.x + tC.y) + tD.x);
            float h1 = h0 - tA.x + tD.y;
            float h2 = h1 - tA.y + tE.x;
            float h3 = h2 - tB.x + tE.y;
            float h4 = h3 - tB.y + tF.x;
            float h5 = h4 - tC.x + tF.y;
            float h6 = h5 - tC.y + tG.x;
            float h7 = h6 - tD.x + tG.y;
            // h is already -K * sum49(d) thanks to the LAM prescale.
            float w;
            w = __builtin_amdgcn_exp2f(-h0); ws[0] += w; ac[0] = fmaf(w, p[0], ac[0]);
            w = __builtin_amdgcn_exp2f(-h1); ws[1] += w; ac[1] = fmaf(w, p[1], ac[1]);
            w = __builtin_amdgcn_exp2f(-h2); ws[2] += w; ac[2] = fmaf(w, p[2], ac[2]);
            w = __builtin_amdgcn_exp2f(-h3); ws[3] += w; ac[3] = fmaf(w, p[3], ac[3]);
            w = __builtin_amdgcn_exp2f(-h4); ws[4] += w; ac[4] = fmaf(w, p[4], ac[4]);
            w = __builtin_amdgcn_exp2f(-h5); ws[5] += w; ac[5] = fmaf(w, p[5], ac[5]);
            w = __builtin_amdgcn_exp2f(-h6); ws[6] += w; ac[6] = fmaf(w, p[6], ac[6]);
            w = __builtin_amdgcn_exp2f(-h7); ws[7] += w; ac[7] = fmaf(w, p7,   ac[7]);
#pragma unroll
            for (int k = 0; k < 6; ++k) p[k] = p[k + 1];
            p[6] = p7;
        }
        if (oxC == 20) { oxC = 0; svC += XSTR; } else { ++oxC; }
    };

    // ---- pipelined offset loop: Bv(i) || C(i-1), 1 barrier/iter ----
    bv_step(0);
    __syncthreads();
#pragma unroll 1
    for (int i = 1; i < 441; ++i) {
        bv_step(i & 1);
        c_step(1 - (i & 1));
        __syncthreads();
    }
    c_step(0);   // offset 440 lives in buffer 0

    if (cact) {
        const float INVLAM = 1.0f / LAM;   // values in ac are LAM-scaled
        float4 oA, oB;
        oA.x = fminf(fmaxf(ac[0] * __builtin_amdgcn_rcpf(ws[0]) * INVLAM, 0.f), 1.f);
        oA.y = fminf(fmaxf(ac[1] * __builtin_amdgcn_rcpf(ws[1]) * INVLAM, 0.f), 1.f);
        oA.z = fminf(fmaxf(ac[2] * __builtin_amdgcn_rcpf(ws[2]) * INVLAM, 0.f), 1.f);
        oA.w = fminf(fmaxf(ac[3] * __builtin_amdgcn_rcpf(ws[3]) * INVLAM, 0.f), 1.f);
        oB.x = fminf(fmaxf(ac[4] * __builtin_amdgcn_rcpf(ws[4]) * INVLAM, 0.f), 1.f);
        oB.y = fminf(fmaxf(ac[5] * __builtin_amdgcn_rcpf(ws[5]) * INVLAM, 0.f), 1.f);
        oB.z = fminf(fmaxf(ac[6] * __builtin_amdgcn_rcpf(ws[6]) * INVLAM, 0.f), 1.f);
        oB.w = fminf(fmaxf(ac[7] * __builtin_amdgcn_rcpf(ws[7]) * INVLAM, 0.f), 1.f);
        float* op = &out[((size_t)blockIdx.z * H + (gy0 + py)) * W + (gx0 + c8)];
        *reinterpret_cast<float4*>(op)     = oA;
        *reinterpret_cast<float4*>(op + 4) = oB;
    }
}

__global__ __launch_bounds__(256)
void nlm_kernel(const float* __restrict__ img_all, float* __restrict__ out,
                int H, int W) {
    __shared__ __align__(16) float xs[XSZ];
    __shared__ __align__(16) float vsh[2 * VS_SZ];
    const int tid = threadIdx.x;
    const int gx0 = blockIdx.x * TS;
    const int gy0 = blockIdx.y * TS;
    const float* img = img_all + (size_t)blockIdx.z * H * W;
    // FAST iff no patch-center row/col (gy0-3..gy0+35 / gx0-3..gx0+34) folds.
    if (gy0 - 3 >= 0 && gy0 + 35 < H && gx0 - 3 >= 0 && gx0 + 34 < W)
        nlm_body<true>(img, out, H, W, gx0, gy0, xs, vsh, tid);
    else
        nlm_body<false>(img, out, H, W, gx0, gy0, xs, vsh, tid);
}

extern "C" void kernel_launch(void* const* d_in, const int* in_sizes, int n_in,
                              void* d_out, int out_size, void* d_ws, size_t ws_size,
                              hipStream_t stream) {
    const float* x = (const float*)d_in[0];
    float* out = (float*)d_out;
    const int H = 1024, W = 1024;
    const int B = in_sizes[0] / (H * W);
    dim3 grid(W / TS, H / TS, B);
    nlm_kernel<<<grid, dim3(256), 0, stream>>>(x, out, H, W);
}

// Round 3
// 2140.939 us; speedup vs baseline: 1.0275x; 1.0275x over previous
//
#include <hip/hip_runtime.h>
#include <cstddef>

// NLM: h=7/255, template 7x7 (TH=3), search 21x21 (SH=10), reflect padding.
// Tile 32x32/block, 256 threads, software-pipelined disjoint wave roles,
// double-buffered vsh, ONE barrier per offset.
// R6: packed-fp32 Bv with R4's PROVEN dataflow (all reads -> all math -> all
// writes; never a ds_read after a ds_write inside a step, because xs/vsh
// aliasing can't be disproven by the compiler and read-hoisting dies).
//   FAST blocks (interior x AND y, 900/1024): Bv = 57 lanes (wave 0), each
//     owning a COLUMN PAIR as float2 -> v_pk_*_f32, ds_read_b64/write_b64.
//   EDGE blocks: R4 scalar Bv (114 lanes, 17 reflected addresses).
// No LAM prescale (R5 lesson: it cost absmax 0 -> 3.9e-3 for ~nothing).
// R2 lesson kept: no unrolling of the offset loop.

typedef float v2f __attribute__((ext_vector_type(2)));

constexpr int TS    = 32;
constexpr int XSTR  = 62;            // EVEN -> float2 (b64) col-pair packing
constexpr int XROWS = 59;            // image rows gy0-13 .. gy0+45
constexpr int XSZ   = XROWS * XSTR;  // 3658
constexpr int VSTR  = 42;            // even (float2-aligned)
constexpr int VROWS = 33;            // 32 + 1 junk row (group-2 uniform writes)
constexpr int VS_SZ = VROWS * VSTR;  // 1386 per buffer

__device__ __forceinline__ int refl(int i, int n) {
    i = (i < 0) ? -i : i;
    return (i >= n) ? (2 * n - 2 - i) : i;
}

template<bool FAST>
__device__ __forceinline__ void nlm_body(const float* __restrict__ img,
                                         float* __restrict__ out,
                                         int H, int W, int gx0, int gy0,
                                         float* __restrict__ xs,
                                         float* __restrict__ vsh, int tid)
{
    // ---- load xs (clip to [0,1], reflect indexing) ----
    for (int e = tid; e < XSZ; e += 256) {
        int i = e / XSTR, j = e - i * XSTR;
        int jj = (j > 57) ? 57 : j;  // cols 58..61: stride pad (never read)
        int gy = refl(gy0 - 13 + i, H);
        int gx = refl(gx0 - 13 + jj, W);
        float v = img[(size_t)gy * W + gx];
        xs[e] = fminf(fmaxf(v, 0.0f), 1.0f);
    }
    __syncthreads();

    // ---- Bv setup ----
    const bool bv = FAST ? (tid < 57) : (tid < 114);
    v2f   uP[17]; int aB = 0;        // FAST state (col-pair packed)
    float uS[17]; int aS[17];        // EDGE state (scalar, reflected rows)
    int   wb = 0;
    if constexpr (FAST) {
        int t  = bv ? tid : 0;
        int g  = t / 19;             // 0..2 row group
        int pp = t - g * 19;         // 0..18 column pair
        int r  = g * 11;             // first output row of this group
        int cc = 2 * pp;             // interior: cols are linear
        aB = r * XSTR + cc;
        wb = r * VSTR + cc;
#pragma unroll
        for (int i = 0; i < 17; ++i)
            uP[i] = *reinterpret_cast<const v2f*>(&xs[(r + i + 10) * XSTR + cc + 10]);
    } else {
        int t  = bv ? tid : 0;
        int g  = t / 38;
        int cc = t - g * 38;
        int r  = g * 11;
        int mxm10 = refl(gx0 + cc - 3, W) - gx0 + 3;
#pragma unroll
        for (int i = 0; i < 17; ++i) {
            int my = refl(gy0 + r + i - 3, H) - gy0 + 13;
            uS[i] = xs[my * XSTR + mxm10 + 10];
            aS[i] = (my - 10) * XSTR + mxm10;
        }
        wb = r * VSTR + cc;
    }

    // ---- C setup ----
    const bool cact = (tid >= 128);
    const int ct = cact ? (tid - 128) : 0;
    const int py = ct >> 2;
    const int c8 = (ct & 3) * 8;
    const int vb = py * VSTR + c8;              // float2-aligned (even)
    int svC = (py + 3) * XSTR + (c8 + 3);       // row base, advances per oy

    int oxB = 0;                                 // uniform ox state machines
    int oxC = 0;

    float p[7];
    float ws[8], ac[8];
#pragma unroll
    for (int k = 0; k < 8; ++k) { ws[k] = 0.f; ac[k] = 0.f; }
    // w = exp(-mean49(d)/H2) = exp2(K * sum49(d))
    const float K = -(65025.0f / 2401.0f) * 1.4426950408889634f;

    auto bv_step = [&](int buf) {
        if (bv) {
            float* vo = vsh + buf * VS_SZ + wb;
            if constexpr (FAST) {
                // READS (all 17, batched; no prior writes to fence against)
                v2f q[17];
#pragma unroll
                for (int i = 0; i < 17; ++i)
                    q[i] = *reinterpret_cast<const v2f*>(&xs[aB + i * XSTR]);
                // MATH
#pragma unroll
                for (int i = 0; i < 17; ++i) {
                    v2f d = uP[i] - q[i];
                    q[i] = d * d;
                }
                v2f s[11];
                s[0] = ((q[0] + q[1]) + (q[2] + q[3])) + ((q[4] + q[5]) + q[6]);
#pragma unroll
                for (int k = 1; k < 11; ++k)
                    s[k] = s[k - 1] + (q[k + 6] - q[k - 1]);
                // WRITES (all 11, after all reads)
#pragma unroll
                for (int k = 0; k < 11; ++k)
                    *reinterpret_cast<v2f*>(&vo[k * VSTR]) = s[k];
                aB += (oxB == 20) ? (XSTR - 20) : 1;
            } else {
                float q[17];
#pragma unroll
                for (int i = 0; i < 17; ++i)
                    q[i] = xs[aS[i]];
#pragma unroll
                for (int i = 0; i < 17; ++i) {
                    float d = uS[i] - q[i];
                    q[i] = d * d;
                }
                float s[11];
                s[0] = ((q[0] + q[1]) + (q[2] + q[3])) + ((q[4] + q[5]) + q[6]);
#pragma unroll
                for (int k = 1; k < 11; ++k)
                    s[k] = s[k - 1] + (q[k + 6] - q[k - 1]);
#pragma unroll
                for (int k = 0; k < 11; ++k)
                    vo[k * VSTR] = s[k];
                int step = (oxB == 20) ? (XSTR - 20) : 1;
#pragma unroll
                for (int i = 0; i < 17; ++i) aS[i] += step;
            }
        }
        oxB = (oxB == 20) ? 0 : (oxB + 1);
    };

    auto c_step = [&](int buf) {
        if (cact) {
            if (oxC == 0) {
#pragma unroll
                for (int k = 0; k < 7; ++k) p[k] = xs[svC + k];
            }
            const v2f* vp = reinterpret_cast<const v2f*>(vsh + buf * VS_SZ + vb);
            v2f tA = vp[0], tB = vp[1], tC = vp[2], tD = vp[3];
            v2f tE = vp[4], tF = vp[5], tG = vp[6];
            float p7 = xs[svC + 7 + oxC];
            float h0 = ((tA.x + tA.y) + (tB.x + tB.y)) + ((tC.x + tC.y) + tD.x);
            float h1 = h0 - tA.x + tD.y;
            float h2 = h1 - tA.y + tE.x;
            float h3 = h2 - tB.x + tE.y;
            float h4 = h3 - tB.y + tF.x;
            float h5 = h4 - tC.x + tF.y;
            float h6 = h5 - tC.y + tG.x;
            float h7 = h6 - tD.x + tG.y;
            float w;
            w = __builtin_amdgcn_exp2f(h0 * K); ws[0] += w; ac[0] = fmaf(w, p[0], ac[0]);
            w = __builtin_amdgcn_exp2f(h1 * K); ws[1] += w; ac[1] = fmaf(w, p[1], ac[1]);
            w = __builtin_amdgcn_exp2f(h2 * K); ws[2] += w; ac[2] = fmaf(w, p[2], ac[2]);
            w = __builtin_amdgcn_exp2f(h3 * K); ws[3] += w; ac[3] = fmaf(w, p[3], ac[3]);
            w = __builtin_amdgcn_exp2f(h4 * K); ws[4] += w; ac[4] = fmaf(w, p[4], ac[4]);
            w = __builtin_amdgcn_exp2f(h5 * K); ws[5] += w; ac[5] = fmaf(w, p[5], ac[5]);
            w = __builtin_amdgcn_exp2f(h6 * K); ws[6] += w; ac[6] = fmaf(w, p[6], ac[6]);
            w = __builtin_amdgcn_exp2f(h7 * K); ws[7] += w; ac[7] = fmaf(w, p7,   ac[7]);
#pragma unroll
            for (int k = 0; k < 6; ++k) p[k] = p[k + 1];
            p[6] = p7;
        }
        if (oxC == 20) { oxC = 0; svC += XSTR; } else { ++oxC; }
    };

    // ---- pipelined offset loop: Bv(i) || C(i-1), 1 barrier/iter ----
    bv_step(0);
    __syncthreads();
#pragma unroll 1
    for (int i = 1; i < 441; ++i) {
        bv_step(i & 1);
        c_step(1 - (i & 1));
        __syncthreads();
    }
    c_step(0);   // offset 440 lives in buffer 0

    if (cact) {
        float4 oA, oB;
        oA.x = fminf(fmaxf(ac[0] * __builtin_amdgcn_rcpf(ws[0]), 0.f), 1.f);
        oA.y = fminf(fmaxf(ac[1] * __builtin_amdgcn_rcpf(ws[1]), 0.f), 1.f);
        oA.z = fminf(fmaxf(ac[2] * __builtin_amdgcn_rcpf(ws[2]), 0.f), 1.f);
        oA.w = fminf(fmaxf(ac[3] * __builtin_amdgcn_rcpf(ws[3]), 0.f), 1.f);
        oB.x = fminf(fmaxf(ac[4] * __builtin_amdgcn_rcpf(ws[4]), 0.f), 1.f);
        oB.y = fminf(fmaxf(ac[5] * __builtin_amdgcn_rcpf(ws[5]), 0.f), 1.f);
        oB.z = fminf(fmaxf(ac[6] * __builtin_amdgcn_rcpf(ws[6]), 0.f), 1.f);
        oB.w = fminf(fmaxf(ac[7] * __builtin_amdgcn_rcpf(ws[7]), 0.f), 1.f);
        float* op = &out[((size_t)blockIdx.z * H + (gy0 + py)) * W + (gx0 + c8)];
        *reinterpret_cast<float4*>(op)     = oA;
        *reinterpret_cast<float4*>(op + 4) = oB;
    }
}

__global__ __launch_bounds__(256)
void nlm_kernel(const float* __restrict__ img_all, float* __restrict__ out,
                int H, int W) {
    __shared__ __align__(16) float xs[XSZ];
    __shared__ __align__(16) float vsh[2 * VS_SZ];
    const int tid = threadIdx.x;
    const int gx0 = blockIdx.x * TS;
    const int gy0 = blockIdx.y * TS;
    const float* img = img_all + (size_t)blockIdx.z * H * W;
    // FAST iff no patch-center row/col (gy0-3..gy0+35 / gx0-3..gx0+34) folds.
    if (gy0 - 3 >= 0 && gy0 + 35 < H && gx0 - 3 >= 0 && gx0 + 34 < W)
        nlm_body<true>(img, out, H, W, gx0, gy0, xs, vsh, tid);
    else
        nlm_body<false>(img, out, H, W, gx0, gy0, xs, vsh, tid);
}

extern "C" void kernel_launch(void* const* d_in, const int* in_sizes, int n_in,
                              void* d_out, int out_size, void* d_ws, size_t ws_size,
                              hipStream_t stream) {
    const float* x = (const float*)d_in[0];
    float* out = (float*)d_out;
    const int H = 1024, W = 1024;
    const int B = in_sizes[0] / (H * W);
    dim3 grid(W / TS, H / TS, B);
    nlm_kernel<<<grid, dim3(256), 0, stream>>>(x, out, H, W);
}

// Round 4
// 1069.632 us; speedup vs baseline: 2.0566x; 2.0016x over previous
//
#include <hip/hip_runtime.h>
#include <cstddef>

// NLM: h=7/255, template 7x7 (TH=3), search 21x21 (SH=10), reflect padding.
// Tile 32x32/block, 256 threads, software-pipelined disjoint wave roles,
// double-buffered vsh, ONE barrier per offset. Structure = R4 (proven 893us).
// R7 changes (occupancy + balance, no geometry change):
//  - vsh stored as fp16 (_Float16): sums s in [0,7], only s<~0.5 matters for
//    w=exp2(K*h); fp16 error -> output ~1e-3 (R5's 3.9e-3 passed tolerance).
//  - XSTR 61->59 (only 58 cols ever read). LDS 25.5 -> 19.0 KB => 8 blocks/CU
//    resident (was 6), 32/32 waves.
//  - Role parity swap per block ((bx^by)&1): Bv on w0/w1 for even blocks, on
//    w2/w3 for odd blocks -> each SIMD gets a mix of light Bv and heavy C
//    waves across resident blocks (waves map to SIMDs by slot).
//  - C's serial 14-op sliding h-chain split into two independent 7-op chains.
// R2 lesson kept: no unrolling of the offset loop.
// R5/R6 lesson: keep 114-lane scalar Bv; the 57-lane packed variant idles a
// SIMD and collapses per-SIMD issue.

typedef _Float16 hf;
typedef _Float16 hf2 __attribute__((ext_vector_type(2)));

constexpr int TS    = 32;
constexpr int XSTR  = 59;            // odd -> mixed-parity bank spread
constexpr int XROWS = 59;            // image rows gy0-13 .. gy0+45
constexpr int XSZ   = XROWS * XSTR;  // 3481
constexpr int VSTR  = 42;            // halves; word stride 21 (odd) -> spread
constexpr int VROWS = 33;            // 32 + 1 junk row (group-2 uniform writes)
constexpr int VS_SZ = VROWS * VSTR;  // 1386 halves per buffer (even)

__device__ __forceinline__ int refl(int i, int n) {
    i = (i < 0) ? -i : i;
    return (i >= n) ? (2 * n - 2 - i) : i;
}

template<bool FAST>
__device__ __forceinline__ void nlm_body(const float* __restrict__ img,
                                         float* __restrict__ out,
                                         int H, int W, int gx0, int gy0,
                                         float* __restrict__ xs,
                                         hf* __restrict__ vsh,
                                         int tid, int parity)
{
    // ---- load xs (clip to [0,1], reflect indexing) ----
    for (int e = tid; e < XSZ; e += 256) {
        int i = e / XSTR, j = e - i * XSTR;
        int jj = (j > 57) ? 57 : j;  // col 58: stride pad (never read)
        int gy = refl(gy0 - 13 + i, H);
        int gx = refl(gx0 - 13 + jj, W);
        float v = img[(size_t)gy * W + gx];
        xs[e] = fminf(fmaxf(v, 0.0f), 1.0f);
    }
    __syncthreads();

    // ---- Bv setup: 114 lanes = 38 cols x 3 row-groups (11 rows, 17 q's) ----
    const int  bvt = parity ? (tid - 142) : tid;
    const bool bv  = ((unsigned)bvt < 114u);
    float u[17];
    int   aB = 0;                    // FAST: single address, +i*XSTR rows
    int   aS[17];                    // EDGE: per-row reflected addresses
    int   wb = 0;
    {
        int t  = bv ? bvt : 0;
        int g  = t / 38;
        int cc = t - g * 38;
        int r  = g * 11;
        int mxm10 = refl(gx0 + cc - 3, W) - gx0 + 3;
        if constexpr (FAST) {
            aB = r * XSTR + mxm10;
#pragma unroll
            for (int i = 0; i < 17; ++i)
                u[i] = xs[(r + i + 10) * XSTR + mxm10 + 10];
        } else {
#pragma unroll
            for (int i = 0; i < 17; ++i) {
                int my = refl(gy0 + r + i - 3, H) - gy0 + 13;
                u[i]  = xs[my * XSTR + mxm10 + 10];
                aS[i] = (my - 10) * XSTR + mxm10;
            }
        }
        wb = r * VSTR + cc;
    }

    // ---- C setup: 128 lanes = 32 rows x 4 groups of 8 cols ----
    const bool cact = parity ? (tid < 128) : (tid >= 128);
    const int ct = cact ? (parity ? tid : (tid - 128)) : 0;
    const int py = ct >> 2;
    const int c8 = (ct & 3) * 8;
    const int vb = py * VSTR + c8;              // halves; even -> hf2-aligned
    int svC = (py + 3) * XSTR + (c8 + 3);       // row base, advances per oy

    int oxB = 0;                                 // uniform ox state machines
    int oxC = 0;

    float p[7];
    float ws[8], ac[8];
#pragma unroll
    for (int k = 0; k < 8; ++k) { ws[k] = 0.f; ac[k] = 0.f; }
    // w = exp(-mean49(d)/H2) = exp2(K * sum49(d))
    const float K = -(65025.0f / 2401.0f) * 1.4426950408889634f;

    auto bv_step = [&](int buf) {
        if (bv) {
            hf* vo = vsh + buf * VS_SZ + wb;
            float q[17];
            if constexpr (FAST) {
#pragma unroll
                for (int i = 0; i < 17; ++i)
                    q[i] = xs[aB + i * XSTR];
            } else {
#pragma unroll
                for (int i = 0; i < 17; ++i)
                    q[i] = xs[aS[i]];
            }
#pragma unroll
            for (int i = 0; i < 17; ++i) {
                float d = u[i] - q[i];
                q[i] = d * d;
            }
            float s[11];
            s[0] = ((q[0] + q[1]) + (q[2] + q[3])) + ((q[4] + q[5]) + q[6]);
#pragma unroll
            for (int k = 1; k < 11; ++k)
                s[k] = s[k - 1] + (q[k + 6] - q[k - 1]);
#pragma unroll
            for (int k = 0; k < 11; ++k)
                vo[k * VSTR] = (hf)s[k];   // group-2 row 32 = junk, never read
            if constexpr (FAST) {
                aB += (oxB == 20) ? (XSTR - 20) : 1;
            } else {
                int step = (oxB == 20) ? (XSTR - 20) : 1;
#pragma unroll
                for (int i = 0; i < 17; ++i) aS[i] += step;
            }
        }
        oxB = (oxB == 20) ? 0 : (oxB + 1);
    };

    auto c_step = [&](int buf) {
        if (cact) {
            if (oxC == 0) {
#pragma unroll
                for (int k = 0; k < 7; ++k) p[k] = xs[svC + k];
            }
            const hf2* vp = reinterpret_cast<const hf2*>(vsh + buf * VS_SZ + vb);
            hf2 A = vp[0], B = vp[1], Cv = vp[2], D = vp[3];
            hf2 E = vp[4], F = vp[5], G = vp[6];
            float a0 = (float)A.x,  a1 = (float)A.y;
            float b0 = (float)B.x,  b1 = (float)B.y;
            float c0 = (float)Cv.x, c1 = (float)Cv.y;
            float d0 = (float)D.x,  d1 = (float)D.y;
            float e0 = (float)E.x,  e1 = (float)E.y;
            float f0 = (float)F.x,  f1 = (float)F.y;
            float g0 = (float)G.x,  g1 = (float)G.y;
            float p7 = xs[svC + 7 + oxC];
            // two independent sliding chains (half the serial depth)
            float h0 = ((a0 + a1) + (b0 + b1)) + ((c0 + c1) + d0);
            float h1 = h0 - a0 + d1;
            float h2 = h1 - a1 + e0;
            float h3 = h2 - b0 + e1;
            float h4 = ((c0 + c1) + (d0 + d1)) + ((e0 + e1) + f0);
            float h5 = h4 - c0 + f1;
            float h6 = h5 - c1 + g0;
            float h7 = h6 - d0 + g1;
            float w;
            w = __builtin_amdgcn_exp2f(h0 * K); ws[0] += w; ac[0] = fmaf(w, p[0], ac[0]);
            w = __builtin_amdgcn_exp2f(h1 * K); ws[1] += w; ac[1] = fmaf(w, p[1], ac[1]);
            w = __builtin_amdgcn_exp2f(h2 * K); ws[2] += w; ac[2] = fmaf(w, p[2], ac[2]);
            w = __builtin_amdgcn_exp2f(h3 * K); ws[3] += w; ac[3] = fmaf(w, p[3], ac[3]);
            w = __builtin_amdgcn_exp2f(h4 * K); ws[4] += w; ac[4] = fmaf(w, p[4], ac[4]);
            w = __builtin_amdgcn_exp2f(h5 * K); ws[5] += w; ac[5] = fmaf(w, p[5], ac[5]);
            w = __builtin_amdgcn_exp2f(h6 * K); ws[6] += w; ac[6] = fmaf(w, p[6], ac[6]);
            w = __builtin_amdgcn_exp2f(h7 * K); ws[7] += w; ac[7] = fmaf(w, p7,   ac[7]);
#pragma unroll
            for (int k = 0; k < 6; ++k) p[k] = p[k + 1];
            p[6] = p7;
        }
        if (oxC == 20) { oxC = 0; svC += XSTR; } else { ++oxC; }
    };

    // ---- pipelined offset loop: Bv(i) || C(i-1), 1 barrier/iter ----
    bv_step(0);
    __syncthreads();
#pragma unroll 1
    for (int i = 1; i < 441; ++i) {
        bv_step(i & 1);
        c_step(1 - (i & 1));
        __syncthreads();
        // barrier fences: C's reads of buf (i-1)&1 from next iter's Bv writes
        // to that buffer, and Bv's writes of buf i&1 from next iter's C reads.
    }
    c_step(0);   // offset 440 lives in buffer 0

    if (cact) {
        float4 oA, oB;
        oA.x = fminf(fmaxf(ac[0] * __builtin_amdgcn_rcpf(ws[0]), 0.f), 1.f);
        oA.y = fminf(fmaxf(ac[1] * __builtin_amdgcn_rcpf(ws[1]), 0.f), 1.f);
        oA.z = fminf(fmaxf(ac[2] * __builtin_amdgcn_rcpf(ws[2]), 0.f), 1.f);
        oA.w = fminf(fmaxf(ac[3] * __builtin_amdgcn_rcpf(ws[3]), 0.f), 1.f);
        oB.x = fminf(fmaxf(ac[4] * __builtin_amdgcn_rcpf(ws[4]), 0.f), 1.f);
        oB.y = fminf(fmaxf(ac[5] * __builtin_amdgcn_rcpf(ws[5]), 0.f), 1.f);
        oB.z = fminf(fmaxf(ac[6] * __builtin_amdgcn_rcpf(ws[6]), 0.f), 1.f);
        oB.w = fminf(fmaxf(ac[7] * __builtin_amdgcn_rcpf(ws[7]), 0.f), 1.f);
        float* op = &out[((size_t)blockIdx.z * H + (gy0 + py)) * W + (gx0 + c8)];
        *reinterpret_cast<float4*>(op)     = oA;
        *reinterpret_cast<float4*>(op + 4) = oB;
    }
}

__global__ __launch_bounds__(256)
void nlm_kernel(const float* __restrict__ img_all, float* __restrict__ out,
                int H, int W) {
    __shared__ __align__(16) float xs[XSZ];
    __shared__ __align__(16) hf vsh[2 * VS_SZ];
    const int tid = threadIdx.x;
    const int gx0 = blockIdx.x * TS;
    const int gy0 = blockIdx.y * TS;
    const int parity = (blockIdx.x ^ blockIdx.y) & 1;
    const float* img = img_all + (size_t)blockIdx.z * H * W;
    // FAST iff no patch-center row (gy0-3..gy0+35) folds at a y-edge.
    if (gy0 - 3 >= 0 && gy0 + 35 < H)
        nlm_body<true>(img, out, H, W, gx0, gy0, xs, vsh, tid, parity);
    else
        nlm_body<false>(img, out, H, W, gx0, gy0, xs, vsh, tid, parity);
}

extern "C" void kernel_launch(void* const* d_in, const int* in_sizes, int n_in,
                              void* d_out, int out_size, void* d_ws, size_t ws_size,
                              hipStream_t stream) {
    const float* x = (const float*)d_in[0];
    float* out = (float*)d_out;
    const int H = 1024, W = 1024;
    const int B = in_sizes[0] / (H * W);
    dim3 grid(W / TS, H / TS, B);
    nlm_kernel<<<grid, dim3(256), 0, stream>>>(x, out, H, W);
}

// Round 5
// 971.992 us; speedup vs baseline: 2.2632x; 1.1005x over previous
//
#include <hip/hip_runtime.h>
#include <cstddef>

// NLM: h=7/255, template 7x7 (TH=3), search 21x21 (SH=10), reflect padding.
// Tile 32x32/block, 256 threads, software-pipelined disjoint wave roles.
// R8 = R4 (proven 893us) + TWO OFFSETS PER BARRIER ROUND:
//   vsh is a 4-deep ring; each round does Bv(i), Bv(i+1), C(i-2), C(i-1),
//   one __syncthreads. Halves barrier count (441 -> 221) and doubles the
//   independent work per C wave per round (two read->h-chain->exp2 streams
//   hide each other's LDS/VALU latency). Buffer b is overwritten 4 offsets
//   (2 barriers) after its consumer read -> safe.
// All math, layouts, and role assignment identical to R4.
// Lessons kept: no unrolling of the 21-step offset loops (R2); scalar 114-lane
// Bv, never 57-lane packed (R5/R6: starves SIMDs); float vsh, never fp16
// (R7: b16 same-word write conflicts +4e7, cvt overhead on C).

constexpr int TS    = 32;
constexpr int XSTR  = 61;            // odd -> benign bank aliasing
constexpr int XROWS = 59;            // image rows gy0-13 .. gy0+45
constexpr int XSZ   = XROWS * XSTR;  // 3599
constexpr int VSTR  = 42;            // even (float2-aligned), 42%8!=0
constexpr int VROWS = 33;            // 32 + 1 junk row (group-2 uniform writes)
constexpr int VS_SZ = VROWS * VSTR;  // 1386 per buffer
constexpr int NBUF  = 4;             // ring depth (2 in flight + 2 consumed)

__device__ __forceinline__ int refl(int i, int n) {
    i = (i < 0) ? -i : i;
    return (i >= n) ? (2 * n - 2 - i) : i;
}

template<bool FAST>
__device__ __forceinline__ void nlm_body(const float* __restrict__ img,
                                         float* __restrict__ out,
                                         int H, int W, int gx0, int gy0,
                                         float* __restrict__ xs,
                                         float* __restrict__ vsh, int tid)
{
    // ---- load xs (clip to [0,1], reflect indexing) ----
    for (int e = tid; e < XSZ; e += 256) {
        int i = e / XSTR, j = e - i * XSTR;
        int jj = (j > 57) ? 57 : j;  // cols 58..60: stride pad (never read)
        int gy = refl(gy0 - 13 + i, H);
        int gx = refl(gx0 - 13 + jj, W);
        float v = img[(size_t)gy * W + gx];
        xs[e] = fminf(fmaxf(v, 0.0f), 1.0f);
    }
    __syncthreads();

    // ---- Bv setup: 114 lanes = 38 cols x 3 row-groups (11 rows, 17 q's) ----
    const bool bv = (tid < 114);
    float u[17];
    int   aB = 0;                    // FAST: single address, +i*XSTR rows
    int   aS[17];                    // EDGE: per-row reflected addresses
    int   wb = 0;
    {
        int t  = bv ? tid : 0;
        int g  = t / 38;
        int cc = t - g * 38;
        int r  = g * 11;
        int mxm10 = refl(gx0 + cc - 3, W) - gx0 + 3;
        if constexpr (FAST) {
            aB = r * XSTR + mxm10;
#pragma unroll
            for (int i = 0; i < 17; ++i)
                u[i] = xs[(r + i + 10) * XSTR + mxm10 + 10];
        } else {
#pragma unroll
            for (int i = 0; i < 17; ++i) {
                int my = refl(gy0 + r + i - 3, H) - gy0 + 13;
                u[i]  = xs[my * XSTR + mxm10 + 10];
                aS[i] = (my - 10) * XSTR + mxm10;
            }
        }
        wb = r * VSTR + cc;
    }

    // ---- C setup: 128 lanes = 32 rows x 4 groups of 8 cols ----
    const bool cact = (tid >= 128);
    const int ct = cact ? (tid - 128) : 0;
    const int py = ct >> 2;
    const int c8 = (ct & 3) * 8;
    const int vb = py * VSTR + c8;              // float2-aligned (even)
    int svC = (py + 3) * XSTR + (c8 + 3);       // row base, advances per oy

    int oxB = 0;                                 // uniform ox state machines
    int oxC = 0;

    float p[7];
    float ws[8], ac[8];
#pragma unroll
    for (int k = 0; k < 8; ++k) { ws[k] = 0.f; ac[k] = 0.f; }
    // w = exp(-mean49(d)/H2) = exp2(K * sum49(d))
    const float K = -(65025.0f / 2401.0f) * 1.4426950408889634f;

    auto bv_step = [&](int buf) {
        if (bv) {
            float* vo = vsh + buf * VS_SZ + wb;
            float q[17];
            if constexpr (FAST) {
#pragma unroll
                for (int i = 0; i < 17; ++i)
                    q[i] = xs[aB + i * XSTR];
            } else {
#pragma unroll
                for (int i = 0; i < 17; ++i)
                    q[i] = xs[aS[i]];
            }
#pragma unroll
            for (int i = 0; i < 17; ++i) {
                float d = u[i] - q[i];
                q[i] = d * d;
            }
            float s[11];
            s[0] = ((q[0] + q[1]) + (q[2] + q[3])) + ((q[4] + q[5]) + q[6]);
#pragma unroll
            for (int k = 1; k < 11; ++k)
                s[k] = s[k - 1] + (q[k + 6] - q[k - 1]);
#pragma unroll
            for (int k = 0; k < 11; ++k)
                vo[k * VSTR] = s[k];   // group-2 row 32 = junk, never read
            if constexpr (FAST) {
                aB += (oxB == 20) ? (XSTR - 20) : 1;
            } else {
                int step = (oxB == 20) ? (XSTR - 20) : 1;
#pragma unroll
                for (int i = 0; i < 17; ++i) aS[i] += step;
            }
        }
        oxB = (oxB == 20) ? 0 : (oxB + 1);
    };

    auto c_step = [&](int buf) {
        if (cact) {
            if (oxC == 0) {
#pragma unroll
                for (int k = 0; k < 7; ++k) p[k] = xs[svC + k];
            }
            const float2* vp =
                reinterpret_cast<const float2*>(vsh + buf * VS_SZ + vb);
            float2 tA = vp[0], tB = vp[1], tC = vp[2], tD = vp[3];
            float2 tE = vp[4], tF = vp[5], tG = vp[6];
            float p7 = xs[svC + 7 + oxC];
            float h0 = ((tA.x + tA.y) + (tB.x + tB.y)) + ((tC.x + tC.y) + tD.x);
            float h1 = h0 - tA.x + tD.y;
            float h2 = h1 - tA.y + tE.x;
            float h3 = h2 - tB.x + tE.y;
            float h4 = h3 - tB.y + tF.x;
            float h5 = h4 - tC.x + tF.y;
            float h6 = h5 - tC.y + tG.x;
            float h7 = h6 - tD.x + tG.y;
            float w;
            w = __builtin_amdgcn_exp2f(h0 * K); ws[0] += w; ac[0] = fmaf(w, p[0], ac[0]);
            w = __builtin_amdgcn_exp2f(h1 * K); ws[1] += w; ac[1] = fmaf(w, p[1], ac[1]);
            w = __builtin_amdgcn_exp2f(h2 * K); ws[2] += w; ac[2] = fmaf(w, p[2], ac[2]);
            w = __builtin_amdgcn_exp2f(h3 * K); ws[3] += w; ac[3] = fmaf(w, p[3], ac[3]);
            w = __builtin_amdgcn_exp2f(h4 * K); ws[4] += w; ac[4] = fmaf(w, p[4], ac[4]);
            w = __builtin_amdgcn_exp2f(h5 * K); ws[5] += w; ac[5] = fmaf(w, p[5], ac[5]);
            w = __builtin_amdgcn_exp2f(h6 * K); ws[6] += w; ac[6] = fmaf(w, p[6], ac[6]);
            w = __builtin_amdgcn_exp2f(h7 * K); ws[7] += w; ac[7] = fmaf(w, p7,   ac[7]);
#pragma unroll
            for (int k = 0; k < 6; ++k) p[k] = p[k + 1];
            p[6] = p7;
        }
        if (oxC == 20) { oxC = 0; svC += XSTR; } else { ++oxC; }
    };

    // ---- pipelined offset loop: {Bv(i),Bv(i+1),C(i-2),C(i-1)} per barrier ----
    bv_step(0);
    bv_step(1);
    __syncthreads();
#pragma unroll 1
    for (int i = 2; i < 440; i += 2) {
        bv_step(i & 3);
        bv_step((i + 1) & 3);
        c_step((i - 2) & 3);
        c_step((i - 1) & 3);
        __syncthreads();
        // buffer b is next overwritten 4 offsets later, i.e. 2 barriers after
        // its consumer's read -> both write-after-read and read-after-write
        // hazards are fenced.
    }
    bv_step(0);    // offset 440 (buf 440&3 = 0; old buf0 consumed at i=438)
    c_step(2);     // offset 438
    c_step(3);     // offset 439
    __syncthreads();
    c_step(0);     // offset 440

    if (cact) {
        float4 oA, oB;
        oA.x = fminf(fmaxf(ac[0] * __builtin_amdgcn_rcpf(ws[0]), 0.f), 1.f);
        oA.y = fminf(fmaxf(ac[1] * __builtin_amdgcn_rcpf(ws[1]), 0.f), 1.f);
        oA.z = fminf(fmaxf(ac[2] * __builtin_amdgcn_rcpf(ws[2]), 0.f), 1.f);
        oA.w = fminf(fmaxf(ac[3] * __builtin_amdgcn_rcpf(ws[3]), 0.f), 1.f);
        oB.x = fminf(fmaxf(ac[4] * __builtin_amdgcn_rcpf(ws[4]), 0.f), 1.f);
        oB.y = fminf(fmaxf(ac[5] * __builtin_amdgcn_rcpf(ws[5]), 0.f), 1.f);
        oB.z = fminf(fmaxf(ac[6] * __builtin_amdgcn_rcpf(ws[6]), 0.f), 1.f);
        oB.w = fminf(fmaxf(ac[7] * __builtin_amdgcn_rcpf(ws[7]), 0.f), 1.f);
        float* op = &out[((size_t)blockIdx.z * H + (gy0 + py)) * W + (gx0 + c8)];
        *reinterpret_cast<float4*>(op)     = oA;
        *reinterpret_cast<float4*>(op + 4) = oB;
    }
}

__global__ __launch_bounds__(256)
void nlm_kernel(const float* __restrict__ img_all, float* __restrict__ out,
                int H, int W) {
    __shared__ __align__(16) float xs[XSZ];
    __shared__ __align__(16) float vsh[NBUF * VS_SZ];
    const int tid = threadIdx.x;
    const int gx0 = blockIdx.x * TS;
    const int gy0 = blockIdx.y * TS;
    const float* img = img_all + (size_t)blockIdx.z * H * W;
    // FAST iff no patch-center row (gy0-3..gy0+35) folds at a y-edge.
    if (gy0 - 3 >= 0 && gy0 + 35 < H)
        nlm_body<true>(img, out, H, W, gx0, gy0, xs, vsh, tid);
    else
        nlm_body<false>(img, out, H, W, gx0, gy0, xs, vsh, tid);
}

extern "C" void kernel_launch(void* const* d_in, const int* in_sizes, int n_in,
                              void* d_out, int out_size, void* d_ws, size_t ws_size,
                              hipStream_t stream) {
    const float* x = (const float*)d_in[0];
    float* out = (float*)d_out;
    const int H = 1024, W = 1024;
    const int B = in_sizes[0] / (H * W);
    dim3 grid(W / TS, H / TS, B);
    nlm_kernel<<<grid, dim3(256), 0, stream>>>(x, out, H, W);
}

// Round 6
// 875.667 us; speedup vs baseline: 2.5122x; 1.1100x over previous
//
#include <hip/hip_runtime.h>
#include <cstddef>

// NLM: h=7/255, template 7x7 (TH=3), search 21x21 (SH=10), reflect padding.
// Tile 32x32/block, 256 threads, software-pipelined disjoint wave roles,
// double-buffered vsh, ONE barrier per offset. Structure = R4 (proven 893us).
// R9 = R4 + EXACT exp-block skip:
//   w = exp2(h*K), K ~= -39.07. f32 exp2 underflows to exactly +0.0 for
//   arg < -150, i.e. h > 3.84. Adding w=0 to ws/ac is a bit-exact no-op, so
//   when ALL lanes of a C wave have min(h0..h7) > 3.95 (arg <= -154), the
//   whole {8 p-reads, 8 muls, 8 exp2, 8 fma, 8 adds} block is skipped behind
//   one wave-uniform __ballot branch (cost: 7 fmin + 1 cmp). Non-skip path is
//   byte-identical R4 math -> absmax stays 0 for any input.
//   p[] shift-register replaced by 8 fresh ds_read_b32 inside the branch
//   (bank-balanced 2/bank; makes skip state-free and moves VALU movs to the
//   less-busy LDS pipe).
// Lessons kept: no unrolling of offset loops (R2); scalar 114-lane Bv, never
// 57-lane packed (R5/R6: starves SIMDs); float vsh, never fp16 (R7: b16
// same-word write conflicts); no extra LDS for barrier-halving (R8:
// occupancy loss > barrier gain).

constexpr int TS    = 32;
constexpr int XSTR  = 61;            // odd -> benign bank aliasing
constexpr int XROWS = 59;            // image rows gy0-13 .. gy0+45
constexpr int XSZ   = XROWS * XSTR;  // 3599
constexpr int VSTR  = 42;            // even (float2-aligned), 42%8!=0
constexpr int VROWS = 33;            // 32 + 1 junk row (group-2 uniform writes)
constexpr int VS_SZ = VROWS * VSTR;  // 1386 per buffer

__device__ __forceinline__ int refl(int i, int n) {
    i = (i < 0) ? -i : i;
    return (i >= n) ? (2 * n - 2 - i) : i;
}

template<bool FAST>
__device__ __forceinline__ void nlm_body(const float* __restrict__ img,
                                         float* __restrict__ out,
                                         int H, int W, int gx0, int gy0,
                                         float* __restrict__ xs,
                                         float* __restrict__ vsh, int tid)
{
    // ---- load xs (clip to [0,1], reflect indexing) ----
    for (int e = tid; e < XSZ; e += 256) {
        int i = e / XSTR, j = e - i * XSTR;
        int jj = (j > 57) ? 57 : j;  // cols 58..60: stride pad (never read)
        int gy = refl(gy0 - 13 + i, H);
        int gx = refl(gx0 - 13 + jj, W);
        float v = img[(size_t)gy * W + gx];
        xs[e] = fminf(fmaxf(v, 0.0f), 1.0f);
    }
    __syncthreads();

    // ---- Bv setup: 114 lanes = 38 cols x 3 row-groups (11 rows, 17 q's) ----
    const bool bv = (tid < 114);
    float u[17];
    int   aB = 0;                    // FAST: single address, +i*XSTR rows
    int   aS[17];                    // EDGE: per-row reflected addresses
    int   wb = 0;
    {
        int t  = bv ? tid : 0;
        int g  = t / 38;
        int cc = t - g * 38;
        int r  = g * 11;
        int mxm10 = refl(gx0 + cc - 3, W) - gx0 + 3;
        if constexpr (FAST) {
            aB = r * XSTR + mxm10;
#pragma unroll
            for (int i = 0; i < 17; ++i)
                u[i] = xs[(r + i + 10) * XSTR + mxm10 + 10];
        } else {
#pragma unroll
            for (int i = 0; i < 17; ++i) {
                int my = refl(gy0 + r + i - 3, H) - gy0 + 13;
                u[i]  = xs[my * XSTR + mxm10 + 10];
                aS[i] = (my - 10) * XSTR + mxm10;
            }
        }
        wb = r * VSTR + cc;
    }

    // ---- C setup: 128 lanes = 32 rows x 4 groups of 8 cols ----
    const bool cact = (tid >= 128);
    const int ct = cact ? (tid - 128) : 0;
    const int py = ct >> 2;
    const int c8 = (ct & 3) * 8;
    const int vb = py * VSTR + c8;              // float2-aligned (even)
    int svC = (py + 3) * XSTR + (c8 + 3);       // row base, advances per oy

    int oxB = 0;                                 // uniform ox state machines
    int oxC = 0;

    float ws[8], ac[8];
#pragma unroll
    for (int k = 0; k < 8; ++k) { ws[k] = 0.f; ac[k] = 0.f; }
    // w = exp(-mean49(d)/H2) = exp2(K * sum49(d))
    const float K = -(65025.0f / 2401.0f) * 1.4426950408889634f;  // ~ -39.07
    const float HSKIP = 3.95f;  // h > 3.95 => h*K <= -154 => exp2 == +0.0f

    auto bv_step = [&](int buf) {
        if (bv) {
            float* vo = vsh + buf * VS_SZ + wb;
            float q[17];
            if constexpr (FAST) {
#pragma unroll
                for (int i = 0; i < 17; ++i)
                    q[i] = xs[aB + i * XSTR];
            } else {
#pragma unroll
                for (int i = 0; i < 17; ++i)
                    q[i] = xs[aS[i]];
            }
#pragma unroll
            for (int i = 0; i < 17; ++i) {
                float d = u[i] - q[i];
                q[i] = d * d;
            }
            float s[11];
            s[0] = ((q[0] + q[1]) + (q[2] + q[3])) + ((q[4] + q[5]) + q[6]);
#pragma unroll
            for (int k = 1; k < 11; ++k)
                s[k] = s[k - 1] + (q[k + 6] - q[k - 1]);
#pragma unroll
            for (int k = 0; k < 11; ++k)
                vo[k * VSTR] = s[k];   // group-2 row 32 = junk, never read
            if constexpr (FAST) {
                aB += (oxB == 20) ? (XSTR - 20) : 1;
            } else {
                int step = (oxB == 20) ? (XSTR - 20) : 1;
#pragma unroll
                for (int i = 0; i < 17; ++i) aS[i] += step;
            }
        }
        oxB = (oxB == 20) ? 0 : (oxB + 1);
    };

    auto c_step = [&](int buf) {
        if (cact) {
            const float2* vp =
                reinterpret_cast<const float2*>(vsh + buf * VS_SZ + vb);
            float2 tA = vp[0], tB = vp[1], tC = vp[2], tD = vp[3];
            float2 tE = vp[4], tF = vp[5], tG = vp[6];
            float h0 = ((tA.x + tA.y) + (tB.x + tB.y)) + ((tC.x + tC.y) + tD.x);
            float h1 = h0 - tA.x + tD.y;
            float h2 = h1 - tA.y + tE.x;
            float h3 = h2 - tB.x + tE.y;
            float h4 = h3 - tB.y + tF.x;
            float h5 = h4 - tC.x + tF.y;
            float h6 = h5 - tC.y + tG.x;
            float h7 = h6 - tD.x + tG.y;
            float m = fminf(fminf(fminf(h0, h1), fminf(h2, h3)),
                            fminf(fminf(h4, h5), fminf(h6, h7)));
            if (__builtin_expect(__ballot(m <= HSKIP) != 0ull, 0)) {
                const int sp = svC + oxC;
                float x0 = xs[sp],     x1 = xs[sp + 1];
                float x2 = xs[sp + 2], x3 = xs[sp + 3];
                float x4 = xs[sp + 4], x5 = xs[sp + 5];
                float x6 = xs[sp + 6], x7 = xs[sp + 7];
                float w;
                w = __builtin_amdgcn_exp2f(h0 * K); ws[0] += w; ac[0] = fmaf(w, x0, ac[0]);
                w = __builtin_amdgcn_exp2f(h1 * K); ws[1] += w; ac[1] = fmaf(w, x1, ac[1]);
                w = __builtin_amdgcn_exp2f(h2 * K); ws[2] += w; ac[2] = fmaf(w, x2, ac[2]);
                w = __builtin_amdgcn_exp2f(h3 * K); ws[3] += w; ac[3] = fmaf(w, x3, ac[3]);
                w = __builtin_amdgcn_exp2f(h4 * K); ws[4] += w; ac[4] = fmaf(w, x4, ac[4]);
                w = __builtin_amdgcn_exp2f(h5 * K); ws[5] += w; ac[5] = fmaf(w, x5, ac[5]);
                w = __builtin_amdgcn_exp2f(h6 * K); ws[6] += w; ac[6] = fmaf(w, x6, ac[6]);
                w = __builtin_amdgcn_exp2f(h7 * K); ws[7] += w; ac[7] = fmaf(w, x7, ac[7]);
            }
            // else: all 8 weights are exactly +0.0f for every lane -> no-op.
        }
        if (oxC == 20) { oxC = 0; svC += XSTR; } else { ++oxC; }
    };

    // ---- pipelined offset loop: Bv(i) || C(i-1), 1 barrier/iter ----
    bv_step(0);
    __syncthreads();
#pragma unroll 1
    for (int i = 1; i < 441; ++i) {
        bv_step(i & 1);
        c_step(1 - (i & 1));
        __syncthreads();
        // barrier fences: C's reads of buf (i-1)&1 from next iter's Bv writes
        // to that buffer, and Bv's writes of buf i&1 from next iter's C reads.
    }
    c_step(0);   // offset 440 lives in buffer 0

    if (cact) {
        float4 oA, oB;
        oA.x = fminf(fmaxf(ac[0] * __builtin_amdgcn_rcpf(ws[0]), 0.f), 1.f);
        oA.y = fminf(fmaxf(ac[1] * __builtin_amdgcn_rcpf(ws[1]), 0.f), 1.f);
        oA.z = fminf(fmaxf(ac[2] * __builtin_amdgcn_rcpf(ws[2]), 0.f), 1.f);
        oA.w = fminf(fmaxf(ac[3] * __builtin_amdgcn_rcpf(ws[3]), 0.f), 1.f);
        oB.x = fminf(fmaxf(ac[4] * __builtin_amdgcn_rcpf(ws[4]), 0.f), 1.f);
        oB.y = fminf(fmaxf(ac[5] * __builtin_amdgcn_rcpf(ws[5]), 0.f), 1.f);
        oB.z = fminf(fmaxf(ac[6] * __builtin_amdgcn_rcpf(ws[6]), 0.f), 1.f);
        oB.w = fminf(fmaxf(ac[7] * __builtin_amdgcn_rcpf(ws[7]), 0.f), 1.f);
        float* op = &out[((size_t)blockIdx.z * H + (gy0 + py)) * W + (gx0 + c8)];
        *reinterpret_cast<float4*>(op)     = oA;
        *reinterpret_cast<float4*>(op + 4) = oB;
    }
}

__global__ __launch_bounds__(256)
void nlm_kernel(const float* __restrict__ img_all, float* __restrict__ out,
                int H, int W) {
    __shared__ __align__(16) float xs[XSZ];
    __shared__ __align__(16) float vsh[2 * VS_SZ];
    const int tid = threadIdx.x;
    const int gx0 = blockIdx.x * TS;
    const int gy0 = blockIdx.y * TS;
    const float* img = img_all + (size_t)blockIdx.z * H * W;
    // FAST iff no patch-center row (gy0-3..gy0+35) folds at a y-edge.
    if (gy0 - 3 >= 0 && gy0 + 35 < H)
        nlm_body<true>(img, out, H, W, gx0, gy0, xs, vsh, tid);
    else
        nlm_body<false>(img, out, H, W, gx0, gy0, xs, vsh, tid);
}

extern "C" void kernel_launch(void* const* d_in, const int* in_sizes, int n_in,
                              void* d_out, int out_size, void* d_ws, size_t ws_size,
                              hipStream_t stream) {
    const float* x = (const float*)d_in[0];
    float* out = (float*)d_out;
    const int H = 1024, W = 1024;
    const int B = in_sizes[0] / (H * W);
    dim3 grid(W / TS, H / TS, B);
    nlm_kernel<<<grid, dim3(256), 0, stream>>>(x, out, H, W);
}